// Round 1
// 496.393 us; speedup vs baseline: 1.0899x; 1.0899x over previous
//
#include <hip/hip_runtime.h>

// 2-layer LSTM: B=2048, T=512, F=60, H=7, PyTorch gate order (i,f,g,o).
//
// TWO-PHASE:
//  Phase 1 (proj_kernel): A[b][t][r] = bias0[r] + Wih0[r,:].x[b,t,:]  (fp32,
//    117 MB in d_ws). v2: fully-coalesced global access on BOTH sides via
//    per-wave LDS transpose tiles (x: col-major stride-33; A: col-major
//    stride-65). FMA accumulation order identical to v1 -> bit-identical A.
//  Phase 2 (rec_kernel): wave = batch (2048 waves, 2/SIMD).
//    lanes 0..27  : layer0 gate rows, step t     (seed = A[b][t][r])
//    lanes 32..59 : layer1 gate rows, step t-1   (seed = bias1[r])
//    Per step: 1 prefetched 4B load + 2x dot7 + activation + 3 shfl gathers
//    + cell update + 14 readlane broadcasts. No LDS, no barriers, no spills.
//    a_in prefetched via an 8-deep register ring (state-independent loads).
// Falls back to the round-3 single kernel if ws_size < 117.4 MB.

#define B_ 2048
#define T_ 512
#define F_ 60
#define H_ 7
#define G4 28
#define BT_ (B_ * T_)
#define L2E 1.4426950408889634f
#define PD 8   // prefetch ring depth

#if __has_builtin(__builtin_amdgcn_exp2f)
#define EXP2(x) __builtin_amdgcn_exp2f(x)
#else
#define EXP2(x) exp2f(x)
#endif

__device__ __forceinline__ float rcpf_(float v) { return __builtin_amdgcn_rcpf(v); }

__device__ __forceinline__ float bcast(float v, int srclane) {
    return __uint_as_float(__builtin_amdgcn_readlane(__float_as_uint(v), srclane));
}

__device__ __forceinline__ float dot7(const float* w, const float* h, float seed) {
    float m01 = fmaf(w[1], h[1], w[0] * h[0]);
    float m23 = fmaf(w[3], h[3], w[2] * h[2]);
    float m45 = fmaf(w[5], h[5], w[4] * h[4]);
    float m6  = fmaf(w[6], h[6], seed);
    return (m01 + m23) + (m45 + m6);
}

// ---------------------------------------------------------------- phase 1
// Per wave: 64 consecutive (b,t) rows. x staged in 2 passes of 32 rows into a
// col-major LDS tile (stride 33 floats: reads conflict-free, writes ~2-way).
// Gates staged col-major (stride 65: writes conflict-free, reads ~2-way) and
// flushed with flat coalesced scalar stores (wave's 1792 floats contiguous).
__global__ __launch_bounds__(256)
void proj_kernel(const float* __restrict__ x, const float* __restrict__ Wih0,
                 const float* __restrict__ bih0, const float* __restrict__ bhh0,
                 float* __restrict__ A)
{
    __shared__ float wsm[G4 * F_];   // 6720 B, broadcast reads (conflict-free)
    __shared__ float bsm[G4];
    __shared__ float xs[4][1980];    // per-wave tile: max(60*33, 28*65) <= 1980

    for (int i = threadIdx.x; i < G4 * F_; i += 256) wsm[i] = Wih0[i];
    if (threadIdx.x < G4) bsm[threadIdx.x] = bih0[threadIdx.x] + bhh0[threadIdx.x];

    const int lane = threadIdx.x & 63;
    const int wv   = threadIdx.x >> 6;
    const int rowW = blockIdx.x * 256 + wv * 64;   // wave's first (b,t) row
    float* __restrict__ xw = xs[wv];

    float xr[F_];

    __syncthreads();

    #pragma unroll
    for (int p = 0; p < 2; ++p) {
        // stage 32 rows = 480 float4s, fully coalesced (16B/lane contiguous)
        const float4* __restrict__ src =
            (const float4*)(x + (size_t)(rowW + 32 * p) * F_);
        #pragma unroll
        for (int j = 0; j < 8; ++j) {
            const int q = lane + 64 * j;
            if (q < 480) {
                float4 v = src[q];
                const int row = q / 15;            // 15 float4 per 60-float row
                const int c0  = (q - row * 15) * 4;
                xw[(c0 + 0) * 33 + row] = v.x;
                xw[(c0 + 1) * 33 + row] = v.y;
                xw[(c0 + 2) * 33 + row] = v.z;
                xw[(c0 + 3) * 33 + row] = v.w;
            }
        }
        __syncthreads();
        // half-wave p pulls its own row into registers (banks (k+rl)%32: free)
        if ((lane >> 5) == p) {
            const int rl = lane & 31;
            #pragma unroll
            for (int k = 0; k < F_; ++k) xr[k] = xw[k * 33 + rl];
        }
        __syncthreads();   // protects pass-1 overwrite / gate-stage overwrite
    }

    // compute 28 gates; accumulation order identical to v1 (bit-exact A)
    #pragma unroll
    for (int rg = 0; rg < 7; ++rg) {
        #pragma unroll
        for (int qq = 0; qq < 4; ++qq) {
            const int r = rg * 4 + qq;
            const float* w = &wsm[r * F_];
            float a0 = bsm[r], a1 = 0.f, a2 = 0.f, a3 = 0.f;
            #pragma unroll
            for (int k = 0; k < F_; k += 4) {
                a0 = fmaf(w[k + 0], xr[k + 0], a0);
                a1 = fmaf(w[k + 1], xr[k + 1], a1);
                a2 = fmaf(w[k + 2], xr[k + 2], a2);
                a3 = fmaf(w[k + 3], xr[k + 3], a3);
            }
            xw[r * 65 + lane] = (a0 + a1) + (a2 + a3);   // col-major stage
        }
    }
    __syncthreads();

    // coalesced flush: wave's 64 rows x 28 gates = 1792 floats contiguous
    float* __restrict__ Aw = A + (size_t)rowW * G4;
    #pragma unroll
    for (int it = 0; it < G4; ++it) {
        const int f   = it * 64 + lane;
        const int row = f / G4;
        const int col = f - row * G4;
        Aw[f] = xw[col * 65 + row];
    }
}

// ---------------------------------------------------------------- phase 2
__global__ __launch_bounds__(256)
void rec_kernel(const float* __restrict__ A,
                const float* __restrict__ Whh0,
                const float* __restrict__ Wih1, const float* __restrict__ Whh1,
                const float* __restrict__ bih1, const float* __restrict__ bhh1,
                float* __restrict__ out)
{
    const int tid   = threadIdx.x;
    const int lane  = tid & 63;
    const bool isL1 = lane >= 32;
    const int g     = lane & 31;
    const int r     = (g < G4) ? g : (G4 - 1);
    const int b     = blockIdx.x * 4 + (tid >> 6);

    float wA[H_], wB[H_];
    #pragma unroll
    for (int v = 0; v < H_; ++v) {
        wA[v] = isL1 ? Wih1[r * H_ + v] : Whh0[r * H_ + v];
        wB[v] = isL1 ? Whh1[r * H_ + v] : 0.f;
    }
    const float bias1 = bih1[r] + bhh1[r];

    const bool isT = (r >= 2 * H_ && r < 3 * H_);   // cell gate -> tanh
    const float KK = isT ? (-2.f * L2E) : (-L2E);
    const float Aa = isT ? 2.f : 1.f;
    const float Ca = isT ? -1.f : 0.f;

    float h0v[H_] = {0, 0, 0, 0, 0, 0, 0};
    float h1v[H_] = {0, 0, 0, 0, 0, 0, 0};
    float c = 0.f, hnew = 0.f;

    // lane's a_in column (clamped for idle lanes -> same cacheline, no extra BW)
    const float* __restrict__ pa = A + (size_t)b * T_ * G4 + r;

    float buf[PD];
    #pragma unroll
    for (int i = 0; i < PD; ++i) buf[i] = pa[i * G4];

    for (int tt = 0; tt < T_; tt += PD) {
        #pragma unroll
        for (int s = 0; s < PD; ++s) {
            const int t = tt + s;
            // issue next prefetch early (state-independent)
            const int tn = (t + PD < T_) ? (t + PD) : (T_ - 1);
            float nb = pa[(size_t)tn * G4];

            float seed = isL1 ? bias1 : buf[s];
            float a = dot7(wA, h0v, seed);
            a = dot7(wB, h1v, a);
            float act = fmaf(Aa, rcpf_(1.f + EXP2(KK * a)), Ca);

            float fg = __shfl(act, lane + 7, 64);
            float gg = __shfl(act, lane + 14, 64);
            float og = __shfl(act, lane + 21, 64);

            float cnew = fmaf(fg, c, act * gg);
            if (t == 0) cnew = isL1 ? 0.f : cnew;   // L1 phantom step
            c = cnew;
            float th = fmaf(2.f, rcpf_(1.f + EXP2(-2.f * L2E * c)), -1.f);
            hnew = og * th;
            // (t==0: L1 hnew = 0 -> broadcasts correct initial h1)

            #pragma unroll
            for (int v = 0; v < H_; ++v) h0v[v] = bcast(hnew, v);
            #pragma unroll
            for (int v = 0; v < H_; ++v) h1v[v] = bcast(hnew, 32 + v);

            buf[s] = nb;
        }
    }

    // epilogue: layer1 step T-1 (consumes h0(T-1), h1(T-2))
    {
        float a = dot7(wA, h0v, isL1 ? bias1 : 0.f);
        a = dot7(wB, h1v, a);
        float act = fmaf(Aa, rcpf_(1.f + EXP2(KK * a)), Ca);
        float fg = __shfl(act, lane + 7, 64);
        float gg = __shfl(act, lane + 14, 64);
        float og = __shfl(act, lane + 21, 64);
        c = fmaf(fg, c, act * gg);
        float th = fmaf(2.f, rcpf_(1.f + EXP2(-2.f * L2E * c)), -1.f);
        hnew = og * th;
    }

    if (isL1 && g < H_) out[(size_t)b * H_ + g] = hnew;
}

// ------------------------------------------- fallback (round-3 kernel, passing)
#define CH 16
#define NCH (T_ / CH)
#define F4 15
#define ROW4 (CH * F4)
#define BPB 4
#define TOT4 (BPB * ROW4)

__device__ __forceinline__ float proj32(const float* pw, const float4* rp, float seed) {
    float s0 = seed, s1 = 0.f, s2 = 0.f, s3 = 0.f;
    #pragma unroll
    for (int j = 0; j < 8; ++j) {
        float4 q = rp[j];
        s0 = fmaf(pw[4 * j + 0], q.x, s0);
        s1 = fmaf(pw[4 * j + 1], q.y, s1);
        s2 = fmaf(pw[4 * j + 2], q.z, s2);
        s3 = fmaf(pw[4 * j + 3], q.w, s3);
    }
    return (s0 + s1) + (s2 + s3);
}

__global__ __launch_bounds__(256, 2)
void lstm2_fallback(const float* __restrict__ x,
                    const float* __restrict__ Wih0, const float* __restrict__ Whh0,
                    const float* __restrict__ bih0, const float* __restrict__ bhh0,
                    const float* __restrict__ Wih1, const float* __restrict__ Whh1,
                    const float* __restrict__ bih1, const float* __restrict__ bhh1,
                    float* __restrict__ out)
{
    __shared__ float4 lds4[2][BPB][ROW4];

    const int tid   = threadIdx.x;
    const int lane  = tid & 63;
    const bool isL1 = lane >= 32;
    const int g     = lane & 31;
    const int r     = (g < G4) ? g : (G4 - 1);
    const int grp   = tid >> 6;
    const int b     = blockIdx.x * BPB + grp;

    float pw[32];
    {
        const int offs = isL1 ? 28 : 0;
        #pragma unroll
        for (int k = 0; k < 32; ++k) pw[k] = Wih0[r * F_ + offs + k];
        if (isL1) { pw[0] = pw[1] = pw[2] = pw[3] = 0.f; }
    }
    float wA[H_], wB[H_];
    #pragma unroll
    for (int v = 0; v < H_; ++v) {
        wA[v] = isL1 ? Wih1[r * H_ + v] : Whh0[r * H_ + v];
        wB[v] = isL1 ? Whh1[r * H_ + v] : 0.f;
    }
    const float bias0 = bih0[r] + bhh0[r];
    const float bias1 = bih1[r] + bhh1[r];

    const bool isT = (r >= 2 * H_ && r < 3 * H_);
    const float KK = isT ? (-2.f * L2E) : (-L2E);
    const float Aa = isT ? 2.f : 1.f;
    const float Ca = isT ? -1.f : 0.f;

    float h0v[H_] = {0, 0, 0, 0, 0, 0, 0};
    float h1v[H_] = {0, 0, 0, 0, 0, 0, 0};
    float c = 0.f, hnew = 0.f;

    const float4* __restrict__ xb =
        (const float4*)(x + (size_t)(blockIdx.x * BPB) * T_ * F_);
    const int XB4 = T_ * F4;
    const int lofs = isL1 ? 7 : 0;
    const float pseed = isL1 ? 0.f : bias0;

    #pragma unroll
    for (int i = 0; i < 4; ++i) {
        int idx = tid + 256 * i;
        if (idx < TOT4) {
            int bl = idx / ROW4;
            int j  = idx - bl * ROW4;
            lds4[0][bl][j] = xb[bl * XB4 + j];
        }
    }
    __syncthreads();

    float a_in;
    {
        float ow = proj32(pw, &lds4[0][grp][0] + lofs, pseed);
        a_in = ow + __shfl(ow, lane ^ 32, 64);
    }

    for (int ch = 0; ch < NCH; ++ch) {
        const int cn = (ch < NCH - 1) ? ch + 1 : ch;
        float4 st[4];
        #pragma unroll
        for (int i = 0; i < 4; ++i) {
            int idx = tid + 256 * i;
            if (idx < TOT4) {
                int bl = idx / ROW4;
                int j  = idx - bl * ROW4;
                st[i] = xb[bl * XB4 + cn * ROW4 + j];
            }
        }

        const int buf = ch & 1;
        const float4* __restrict__ rowb = &lds4[buf][grp][0] + lofs;

        #pragma unroll
        for (int s = 0; s < CH; ++s) {
            float seed = isL1 ? bias1 : a_in;
            float a = dot7(wA, h0v, seed);
            a = dot7(wB, h1v, a);
            float act = fmaf(Aa, rcpf_(1.f + EXP2(KK * a)), Ca);

            float fg = __shfl(act, lane + 7, 64);
            float gg = __shfl(act, lane + 14, 64);
            float og = __shfl(act, lane + 21, 64);

            float cnew = fmaf(fg, c, act * gg);
            if (ch == 0 && s == 0) cnew = isL1 ? 0.f : cnew;
            c = cnew;
            float th = fmaf(2.f, rcpf_(1.f + EXP2(-2.f * L2E * c)), -1.f);
            hnew = og * th;

            #pragma unroll
            for (int v = 0; v < H_; ++v) h0v[v] = bcast(hnew, v);
            if (ch > 0 || s > 0) {
                #pragma unroll
                for (int v = 0; v < H_; ++v) h1v[v] = bcast(hnew, 32 + v);
            }

            if (s < CH - 1) {
                float ow = proj32(pw, rowb + (s + 1) * F4, pseed);
                a_in = ow + __shfl(ow, lane ^ 32, 64);
            }
        }

        #pragma unroll
        for (int i = 0; i < 4; ++i) {
            int idx = tid + 256 * i;
            if (idx < TOT4) {
                int bl = idx / ROW4;
                int j  = idx - bl * ROW4;
                lds4[buf ^ 1][bl][j] = st[i];
            }
        }
        __syncthreads();

        if (ch < NCH - 1) {
            float ow = proj32(pw, &lds4[buf ^ 1][grp][0] + lofs, pseed);
            a_in = ow + __shfl(ow, lane ^ 32, 64);
        }
    }

    {
        float a = dot7(wA, h0v, isL1 ? bias1 : 0.f);
        a = dot7(wB, h1v, a);
        float act = fmaf(Aa, rcpf_(1.f + EXP2(KK * a)), Ca);
        float fg = __shfl(act, lane + 7, 64);
        float gg = __shfl(act, lane + 14, 64);
        float og = __shfl(act, lane + 21, 64);
        c = fmaf(fg, c, act * gg);
        float th = fmaf(2.f, rcpf_(1.f + EXP2(-2.f * L2E * c)), -1.f);
        hnew = og * th;
    }

    if (isL1 && g < H_) out[(size_t)b * H_ + g] = hnew;
}

extern "C" void kernel_launch(void* const* d_in, const int* in_sizes, int n_in,
                              void* d_out, int out_size, void* d_ws, size_t ws_size,
                              hipStream_t stream) {
    const float* x    = (const float*)d_in[0];
    const float* Wih0 = (const float*)d_in[1];
    const float* Whh0 = (const float*)d_in[2];
    const float* bih0 = (const float*)d_in[3];
    const float* bhh0 = (const float*)d_in[4];
    const float* Wih1 = (const float*)d_in[5];
    const float* Whh1 = (const float*)d_in[6];
    const float* bih1 = (const float*)d_in[7];
    const float* bhh1 = (const float*)d_in[8];
    float* out = (float*)d_out;

    const size_t need = (size_t)BT_ * G4 * sizeof(float);   // 117,440,512 B
    if (ws_size >= need) {
        float* A = (float*)d_ws;
        proj_kernel<<<dim3(BT_ / 256), dim3(256), 0, stream>>>(x, Wih0, bih0, bhh0, A);
        rec_kernel<<<dim3(B_ / 4), dim3(256), 0, stream>>>(A, Whh0, Wih1, Whh1,
                                                           bih1, bhh1, out);
    } else {
        lstm2_fallback<<<dim3(B_ / BPB), dim3(256), 0, stream>>>(
            x, Wih0, Whh0, bih0, bhh0, Wih1, Whh1, bih1, bhh1, out);
    }
}